// Round 14
// baseline (1637.296 us; speedup 1.0000x reference)
//
#include <hip/hip_runtime.h>

#define N_PTS 4096
#define B_SZ  8
#define M_OUT 1024
#define NS    64
#define CIN   128
#define COUT  256

typedef float v2f __attribute__((ext_vector_type(2)));

// Wave-64 max reduce via DPP (row_shr 1/2/4/8, bcast15, bcast31), result
// broadcast through readlane(63). Bit-exact fmax tree. HW-VALIDATED (v2 776us,
// R6 738us, R8/R9 726us passing runs).
__device__ __forceinline__ float dpp_max_f32(float v) {
  int x = __builtin_bit_cast(int, v);
#define STG(C)                                                              \
  {                                                                         \
    int y = __builtin_amdgcn_update_dpp(x, x, C, 0xF, 0xF, false);          \
    float a = __builtin_bit_cast(float, x);                                 \
    float b2 = __builtin_bit_cast(float, y);                                \
    a = fmaxf(a, b2);                                                       \
    x = __builtin_bit_cast(int, a);                                         \
  }
  STG(0x111) STG(0x112) STG(0x114) STG(0x118) STG(0x142) STG(0x143)
#undef STG
  return __builtin_bit_cast(float, __builtin_amdgcn_readlane(x, 63));
}

// ---------------------------------------------------------------------------
// 1) FUSED fps + conv. ONE-WAVE fps per batch: no barrier / slots / combine in
//    the step loop (measured: cross-wave machinery was ~1500cyc of the
//    1730cyc step at 4 waves). R12 failed at VGPR=136: compiler REMATERIALIZED
//    px/py/pz from LDS each step with 32-way bank conflicts. Two fixes:
//    (a) amdgpu_waves_per_eu(1,1): allocator target = 1 wave/EU, no motive to
//        remat below the 512-VGPR cap (~290 needed);
//    (b) TRANSPOSED staging layout — point p at slot (p&63)*64 + (p>>6) — so
//        even if remat happens, lane t's step-j read (slot j*64+t) is
//        conflict-free (bank = t%32). Both outcomes beat the 4-wave floor.
//    Lane t owns [64t, 64t+64): lane order == index order, so the validated
//    ballot->ffs->readlane argmax keeps jnp.argmax's lowest-index tie-break
//    structurally. Waves 1-3 stage xyz then exit. Winners staged in LDS,
//    dumped at the end. Conv branch byte-identical (1 blk/CU under the
//    attribute => ~2x slower, still hidden in the fps window).
// ---------------------------------------------------------------------------
__global__ __launch_bounds__(256)
__attribute__((amdgpu_waves_per_eu(1, 1))) void fps_conv_kernel(
    const float* __restrict__ xyz, int* __restrict__ fps_idx,
    const float* __restrict__ F, const float* __restrict__ W,
    float* __restrict__ Z) {
  __shared__ __align__(16) float smem[13360];
  if (blockIdx.x < 8) {
#pragma clang fp contract(off)
    float* lx = smem;                    // transposed: pt p at (p&63)*64+(p>>6)
    float* ly = smem + 4096;
    float* lz = smem + 8192;
    int* wlds = (int*)(smem + 12288);    // [1024] winner history
    const int b = blockIdx.x, t = threadIdx.x;
    const float* base = xyz + b * N_PTS * 3;
    for (int e = t; e < N_PTS; e += 256) {
      const int s = (e & 63) * 64 + (e >> 6);
      lx[s] = base[e * 3 + 0];
      ly[s] = base[e * 3 + 1];
      lz[s] = base[e * 3 + 2];
    }
    __syncthreads();
    if (t >= 64) return;  // single-wave FPS from here on
    v2f px[32], py[32], pz[32], m2[32];
#pragma unroll
    for (int j = 0; j < 32; ++j) {
      const int s0 = (2 * j) * 64 + t, s1 = (2 * j + 1) * 64 + t;
      px[j] = (v2f){lx[s0], lx[s1]};
      py[j] = (v2f){ly[s0], ly[s1]};
      pz[j] = (v2f){lz[s0], lz[s1]};
      m2[j] = (v2f){1e10f, 1e10f};
    }
    int cur = 0;
    float cx = lx[0], cy = ly[0], cz = lz[0];  // point 0 -> slot 0
    for (int i = 0; i < M_OUT; ++i) {
      if (t == 0) wlds[i] = cur;
      float bv = -1.0f;
      int bj = 0;  // local slot 0..63 (inline-const cndmask updates)
#pragma unroll
      for (int j = 0; j < 32; ++j) {
        v2f dx = px[j] - cx, dy = py[j] - cy, dz = pz[j] - cz;
        v2f d = dx * dx + dy * dy;  // contract(off): numpy op order, no FMA
        d = d + dz * dz;
        v2f md = __builtin_elementwise_min(m2[j], d);
        m2[j] = md;
        // ascending j, strict > => lowest tied index within the lane
        if (md.x > bv) { bv = md.x; bj = 2 * j; }
        if (md.y > bv) { bv = md.y; bj = 2 * j + 1; }
      }
      const float mv = dpp_max_f32(bv);  // wave max, all lanes (validated)
      // Lowest tied lane holds the lowest tied global index (structural).
      unsigned long long tied = __ballot(bv == mv);  // non-empty
      const int fl = __ffsll(tied) - 1;              // first tied lane (SGPR)
      const int bi = t * 64 + bj;                    // own candidate index
      const int widx = __builtin_amdgcn_readlane(bi, fl);
      const int ws = (widx & 63) * 64 + (widx >> 6);
      cx = lx[ws]; cy = ly[ws]; cz = lz[ws];  // uniform broadcast read
      cur = widx;
    }
    for (int e = t; e < M_OUT; e += 64) fps_idx[b * M_OUT + e] = wlds[e];
  } else {
    // ---- conv: Z[b][n][o] = sum_c F[b][c][n] * W[o][c] (R8-validated) ----
    float (*Bs)[68] = (float(*)[68])smem;          // [128][68]
    float (*As)[68] = (float(*)[68])(smem + 8704); // [32][68]
    const int bid = blockIdx.x - 8;
    const int n0 = (bid & 63) * 64;
    const int o0 = ((bid >> 6) & 3) * 64;
    const int b = bid >> 8;
    const int tid = threadIdx.x;
    for (int l = 0; l < 32; ++l) {
      int e = l * 256 + tid;
      int c = e & 127, oo = e >> 7;
      Bs[c][oo] = W[(o0 + oo) * CIN + c];
    }
    float acc[4][4] = {};
    const int tx = tid & 15, ty = tid >> 4;
    const float* Fb = F + b * CIN * N_PTS;
    for (int c0 = 0; c0 < CIN; c0 += 32) {
      __syncthreads();
      for (int l = 0; l < 8; ++l) {
        int e = l * 256 + tid;
        int nn = e & 63, cc = e >> 6;
        As[cc][nn] = Fb[(c0 + cc) * N_PTS + n0 + nn];
      }
      __syncthreads();
#pragma unroll
      for (int cc = 0; cc < 32; ++cc) {
        float4 a = *(const float4*)&As[cc][tx * 4];
        float4 w4 = *(const float4*)&Bs[c0 + cc][ty * 4];
        acc[0][0] += a.x * w4.x; acc[0][1] += a.x * w4.y; acc[0][2] += a.x * w4.z; acc[0][3] += a.x * w4.w;
        acc[1][0] += a.y * w4.x; acc[1][1] += a.y * w4.y; acc[1][2] += a.y * w4.z; acc[1][3] += a.y * w4.w;
        acc[2][0] += a.z * w4.x; acc[2][1] += a.z * w4.y; acc[2][2] += a.z * w4.z; acc[2][3] += a.z * w4.w;
        acc[3][0] += a.w * w4.x; acc[3][1] += a.w * w4.y; acc[3][2] += a.w * w4.z; acc[3][3] += a.w * w4.w;
      }
    }
    float* Zb = Z + (size_t)(b * N_PTS + n0) * COUT + o0;
#pragma unroll
    for (int i = 0; i < 4; ++i) {
      int nn = tx * 4 + i;
      float4 v = make_float4(acc[i][0], acc[i][1], acc[i][2], acc[i][3]);
      *(float4*)&Zb[(size_t)nn * COUT + ty * 4] = v;
    }
  }
}

// ---------------------------------------------------------------------------
// 2) FUSED ball query + gather/max-pool/BN/ReLU (R9-validated, byte-identical).
// ---------------------------------------------------------------------------
__global__ __launch_bounds__(256) void ballq_pool_kernel(
    const float* __restrict__ xyz, const int* __restrict__ fps_idx,
    const float* __restrict__ Z, const float* __restrict__ bias,
    const float* __restrict__ gamma, const float* __restrict__ beta,
    const float* __restrict__ rmean, const float* __restrict__ rvar,
    float* __restrict__ out) {
  __shared__ float T[COUT][9];
  __shared__ __align__(16) int sidx[8 * NS];
  const int b = blockIdx.x & 7;            // XCD-locality swizzle
  const int m0 = (blockIdx.x >> 3) * 8;    // 128 m-tiles of 8 per batch
  const int lane = threadIdx.x & 63, wv = threadIdx.x >> 6;
  const float* base = xyz + b * N_PTS * 3;
  {
#pragma clang fp contract(off)
    for (int cc2 = 0; cc2 < 2; ++cc2) {
      const int c = 2 * wv + cc2;
      const int cidx = fps_idx[b * M_OUT + m0 + c];
      const float cx = base[cidx * 3 + 0], cy = base[cidx * 3 + 1],
                  cz = base[cidx * 3 + 2];
      int* srow = sidx + c * NS;
      int cnt = 0, first = 0;
      for (int ch = 0; ch < N_PTS / 64 && cnt < NS; ++ch) {
        const int n = ch * 64 + lane;
        float dx = base[n * 3 + 0] - cx;
        float dy = base[n * 3 + 1] - cy;
        float dz = base[n * 3 + 2] - cz;
        float d = dx * dx + dy * dy;
        d = d + dz * dz;
        const bool inb = d < 0.1024f;  // f32(RADIUS^2)
        unsigned long long mask = __ballot(inb);
        if (cnt == 0 && mask) first = ch * 64 + (__ffsll(mask) - 1);
        const int pos = cnt + __popcll(mask & ((1ull << lane) - 1ull));
        if (inb && pos < NS) srow[pos] = n;
        cnt += (int)__popcll(mask);
      }
      if (lane >= cnt) srow[lane] = first;  // pad (center => cnt >= 1)
    }
  }
  __syncthreads();
  const int o = threadIdx.x;
  const float sc = gamma[o] * (1.0f / sqrtf(rvar[o] + 1e-5f));
  const float bo = bias[o], mo = rmean[o], bt = beta[o];
  const float* Zb = Z + (size_t)b * N_PTS * COUT;
  for (int mi = 0; mi < 8; ++mi) {
    float b0 = -1e30f, b1 = -1e30f, b2 = -1e30f, b3 = -1e30f;
#pragma unroll
    for (int s = 0; s < NS; s += 4) {
      int4 iv = *(const int4*)&sidx[mi * NS + s];
      b0 = fmaxf(b0, Zb[(size_t)iv.x * COUT + o]);
      b1 = fmaxf(b1, Zb[(size_t)iv.y * COUT + o]);
      b2 = fmaxf(b2, Zb[(size_t)iv.z * COUT + o]);
      b3 = fmaxf(b3, Zb[(size_t)iv.w * COUT + o]);
    }
    float best = fmaxf(fmaxf(b0, b1), fmaxf(b2, b3));
    float t = best + bo;
    t = (t - mo) * sc + bt;
    T[o][mi] = fmaxf(t, 0.0f);
  }
  __syncthreads();
  for (int l = 0; l < 8; ++l) {
    int e = l * 256 + (int)threadIdx.x;
    int mm = e & 7, oo = e >> 3;
    out[(size_t)(b * COUT + oo) * M_OUT + m0 + mm] = T[oo][mm];
  }
}

extern "C" void kernel_launch(void* const* d_in, const int* in_sizes, int n_in,
                              void* d_out, int out_size, void* d_ws, size_t ws_size,
                              hipStream_t stream) {
  const float* xyz      = (const float*)d_in[0];
  const float* features = (const float*)d_in[1];
  const float* W        = (const float*)d_in[2];
  const float* bias     = (const float*)d_in[3];
  const float* gamma    = (const float*)d_in[4];
  const float* beta     = (const float*)d_in[5];
  const float* rmean    = (const float*)d_in[6];
  const float* rvar     = (const float*)d_in[7];
  float* out = (float*)d_out;

  char* ws = (char*)d_ws;
  int* fps  = (int*)ws;                                  // 32 KB
  float* Z  = (float*)(ws + (64 << 10) + (2 << 20));     // 33.5 MB

  fps_conv_kernel<<<8 + 2048, 256, 0, stream>>>(xyz, fps, features, W, Z);
  ballq_pool_kernel<<<B_SZ * (M_OUT / 8), 256, 0, stream>>>(
      xyz, fps, Z, bias, gamma, beta, rmean, rvar, out);
}

// Round 15
// 841.219 us; speedup vs baseline: 1.9463x; 1.9463x over previous
//
#include <hip/hip_runtime.h>

#define N_PTS 4096
#define B_SZ  8
#define M_OUT 1024
#define NS    64
#define CIN   128
#define COUT  256

typedef float v2f __attribute__((ext_vector_type(2)));

// Wave-64 max reduce via DPP (row_shr 1/2/4/8, bcast15, bcast31), result
// broadcast through readlane(63). Bit-exact fmax tree. HW-VALIDATED (v2 776us,
// R6 738us, R8/R9 726us passing runs).
__device__ __forceinline__ float dpp_max_f32(float v) {
  int x = __builtin_bit_cast(int, v);
#define STG(C)                                                              \
  {                                                                         \
    int y = __builtin_amdgcn_update_dpp(x, x, C, 0xF, 0xF, false);          \
    float a = __builtin_bit_cast(float, x);                                 \
    float b2 = __builtin_bit_cast(float, y);                                \
    a = fmaxf(a, b2);                                                       \
    x = __builtin_bit_cast(int, a);                                         \
  }
  STG(0x111) STG(0x112) STG(0x114) STG(0x118) STG(0x142) STG(0x143)
#undef STG
  return __builtin_bit_cast(float, __builtin_amdgcn_readlane(x, 63));
}

// ---------------------------------------------------------------------------
// 1) FUSED fps + conv — byte-identical to the R9-validated 726us version.
//    FPS: 4 waves/256 thr (measured optimum: 1-wave variants remat from LDS
//    at 3500cyc/step — R12/R13; 8 waves adds +155cyc/wave — R7). conv rides
//    the idle ~248 CUs inside the fps window (R8/R9-validated overlap).
// ---------------------------------------------------------------------------
__global__ __launch_bounds__(256) void fps_conv_kernel(
    const float* __restrict__ xyz, int* __restrict__ fps_idx,
    const float* __restrict__ F, const float* __restrict__ W,
    float* __restrict__ Z) {
  __shared__ __align__(16) float smem[13360];
  if (blockIdx.x < 8) {
#pragma clang fp contract(off)
    // ---- FPS (R6-validated) ----
    float* lx = smem;                         // [4096]
    float* ly = smem + 4096;                  // [4096]
    float* lz = smem + 8192;                  // [4096]
    float4 (*sl)[4] = (float4(*)[4])(smem + 12288);  // [2][4]
    int (*siw)[4] = (int(*)[4])(smem + 12320);       // [2][4]
    int* wlds = (int*)(smem + 12328);                // [1024]
    const int b = blockIdx.x, t = threadIdx.x;
    const int lane = t & 63, wv = t >> 6;
    const float* base = xyz + b * N_PTS * 3;
    for (int e = t; e < N_PTS; e += 256) {
      lx[e] = base[e * 3 + 0];
      ly[e] = base[e * 3 + 1];
      lz[e] = base[e * 3 + 2];
    }
    __syncthreads();
    const int nb = t * 16;  // contiguous: thread t owns [16t, 16t+16)
    v2f px[8], py[8], pz[8], m2[8];
#pragma unroll
    for (int j = 0; j < 8; ++j) {
      int n0 = nb + 2 * j;
      px[j] = (v2f){lx[n0], lx[n0 + 1]};
      py[j] = (v2f){ly[n0], ly[n0 + 1]};
      pz[j] = (v2f){lz[n0], lz[n0 + 1]};
      m2[j] = (v2f){1e10f, 1e10f};
    }
    int cur = 0;
    float cx = lx[0], cy = ly[0], cz = lz[0];
    for (int i = 0; i < M_OUT; ++i) {
      if (t == 0) wlds[i] = cur;
      float bv = -1.0f;
      int bj = 0;
#pragma unroll
      for (int j = 0; j < 8; ++j) {
        v2f dx = px[j] - cx, dy = py[j] - cy, dz = pz[j] - cz;
        v2f d = dx * dx + dy * dy;  // contract(off): numpy op order, no FMA
        d = d + dz * dz;
        v2f md = __builtin_elementwise_min(m2[j], d);
        m2[j] = md;
        // ascending j, strict > => lowest tied index within the thread
        if (md.x > bv) { bv = md.x; bj = 2 * j; }
        if (md.y > bv) { bv = md.y; bj = 2 * j + 1; }
      }
      const float mv = dpp_max_f32(bv);  // wave max, all lanes (validated)
      unsigned long long tied = __ballot(bv == mv);  // non-empty
      const int fl = __ffsll(tied) - 1;              // first tied lane
      const int bi = nb + bj;
      const int widx = __builtin_amdgcn_readlane(bi, fl);
      // Pre-barrier uniform LDS broadcast read; hides in barrier skew.
      const float wx = lx[widx], wy = ly[widx], wz = lz[widx];
      const int p = i & 1;
      if (lane == 0) {
        sl[p][wv] = make_float4(mv, wx, wy, wz);
        siw[p][wv] = widx;
      }
      __syncthreads();  // the only barrier per step (parity-buffered slots)
      float4 s0 = sl[p][0], s1 = sl[p][1], s2 = sl[p][2], s3 = sl[p][3];
      int i0 = siw[p][0], i1 = siw[p][1], i2 = siw[p][2], i3 = siw[p][3];
      float gv = s0.x, gx = s0.y, gy = s0.z, gz = s0.w;
      int gi = i0;
      bool bt;
      bt = (s1.x > gv) || (s1.x == gv && i1 < gi);
      if (bt) { gv = s1.x; gi = i1; gx = s1.y; gy = s1.z; gz = s1.w; }
      bt = (s2.x > gv) || (s2.x == gv && i2 < gi);
      if (bt) { gv = s2.x; gi = i2; gx = s2.y; gy = s2.z; gz = s2.w; }
      bt = (s3.x > gv) || (s3.x == gv && i3 < gi);
      if (bt) { gv = s3.x; gi = i3; gx = s3.y; gy = s3.z; gz = s3.w; }
      cur = gi; cx = gx; cy = gy; cz = gz;
    }
    __syncthreads();
    for (int e = t; e < M_OUT; e += 256) fps_idx[b * M_OUT + e] = wlds[e];
  } else {
    // ---- conv: Z[b][n][o] = sum_c F[b][c][n] * W[o][c] (R8-validated) ----
    float (*Bs)[68] = (float(*)[68])smem;          // [128][68]
    float (*As)[68] = (float(*)[68])(smem + 8704); // [32][68]
    const int bid = blockIdx.x - 8;
    const int n0 = (bid & 63) * 64;
    const int o0 = ((bid >> 6) & 3) * 64;
    const int b = bid >> 8;
    const int tid = threadIdx.x;
    for (int l = 0; l < 32; ++l) {
      int e = l * 256 + tid;
      int c = e & 127, oo = e >> 7;
      Bs[c][oo] = W[(o0 + oo) * CIN + c];
    }
    float acc[4][4] = {};
    const int tx = tid & 15, ty = tid >> 4;
    const float* Fb = F + b * CIN * N_PTS;
    for (int c0 = 0; c0 < CIN; c0 += 32) {
      __syncthreads();
      for (int l = 0; l < 8; ++l) {
        int e = l * 256 + tid;
        int nn = e & 63, cc = e >> 6;
        As[cc][nn] = Fb[(c0 + cc) * N_PTS + n0 + nn];
      }
      __syncthreads();
#pragma unroll
      for (int cc = 0; cc < 32; ++cc) {
        float4 a = *(const float4*)&As[cc][tx * 4];
        float4 w4 = *(const float4*)&Bs[c0 + cc][ty * 4];
        acc[0][0] += a.x * w4.x; acc[0][1] += a.x * w4.y; acc[0][2] += a.x * w4.z; acc[0][3] += a.x * w4.w;
        acc[1][0] += a.y * w4.x; acc[1][1] += a.y * w4.y; acc[1][2] += a.y * w4.z; acc[1][3] += a.y * w4.w;
        acc[2][0] += a.z * w4.x; acc[2][1] += a.z * w4.y; acc[2][2] += a.z * w4.z; acc[2][3] += a.z * w4.w;
        acc[3][0] += a.w * w4.x; acc[3][1] += a.w * w4.y; acc[3][2] += a.w * w4.z; acc[3][3] += a.w * w4.w;
      }
    }
    float* Zb = Z + (size_t)(b * N_PTS + n0) * COUT + o0;
#pragma unroll
    for (int i = 0; i < 4; ++i) {
      int nn = tx * 4 + i;
      float4 v = make_float4(acc[i][0], acc[i][1], acc[i][2], acc[i][3]);
      *(float4*)&Zb[(size_t)nn * COUT + ty * 4] = v;
    }
  }
}

// ---------------------------------------------------------------------------
// 2) FUSED ball query + gather/max-pool/BN/ReLU — tail de-latencied vs R9:
//    512 threads (8 waves, 32 waves/CU at 1024 blocks): phase 1 = ONE center
//    per wave (was 2 serial); phase 2 = 2 mi in parallel (half = tid>>8) with
//    8 independent gather chains (was 4) => dependent L2-latency chain depth
//    16 -> 8. All reorderings are fmax-only => bit-identical. Scan logic,
//    tie-handling, epilogue, output layout: R9-validated, unchanged.
// ---------------------------------------------------------------------------
__global__ __launch_bounds__(512) void ballq_pool_kernel(
    const float* __restrict__ xyz, const int* __restrict__ fps_idx,
    const float* __restrict__ Z, const float* __restrict__ bias,
    const float* __restrict__ gamma, const float* __restrict__ beta,
    const float* __restrict__ rmean, const float* __restrict__ rvar,
    float* __restrict__ out) {
  __shared__ float T[COUT][9];
  __shared__ __align__(16) int sidx[8 * NS];
  const int b = blockIdx.x & 7;            // XCD-locality swizzle
  const int m0 = (blockIdx.x >> 3) * 8;    // 128 m-tiles of 8 per batch
  const int lane = threadIdx.x & 63, wv = threadIdx.x >> 6;  // wv in 0..7
  const float* base = xyz + b * N_PTS * 3;
  // ---- phase 1: ball query, center m0+wv per wave (validated scan) ----
  {
#pragma clang fp contract(off)
    const int cidx = fps_idx[b * M_OUT + m0 + wv];
    const float cx = base[cidx * 3 + 0], cy = base[cidx * 3 + 1],
                cz = base[cidx * 3 + 2];
    int* srow = sidx + wv * NS;
    int cnt = 0, first = 0;
    for (int ch = 0; ch < N_PTS / 64 && cnt < NS; ++ch) {
      const int n = ch * 64 + lane;
      float dx = base[n * 3 + 0] - cx;
      float dy = base[n * 3 + 1] - cy;
      float dz = base[n * 3 + 2] - cz;
      float d = dx * dx + dy * dy;
      d = d + dz * dz;
      const bool inb = d < 0.1024f;  // f32(RADIUS^2)
      unsigned long long mask = __ballot(inb);
      if (cnt == 0 && mask) first = ch * 64 + (__ffsll(mask) - 1);
      const int pos = cnt + __popcll(mask & ((1ull << lane) - 1ull));
      if (inb && pos < NS) srow[pos] = n;
      cnt += (int)__popcll(mask);
    }
    if (lane >= cnt) srow[lane] = first;  // pad (center => cnt >= 1)
  }
  __syncthreads();
  // ---- phase 2: gather + max-pool + BN + ReLU (8 chains, 2 mi parallel) ----
  const int o = threadIdx.x & 255;
  const int half = threadIdx.x >> 8;  // mi parity
  const float sc = gamma[o] * (1.0f / sqrtf(rvar[o] + 1e-5f));
  const float bo = bias[o], mo = rmean[o], bt = beta[o];
  const float* Zb = Z + (size_t)b * N_PTS * COUT;
  for (int k = 0; k < 4; ++k) {
    const int mi = 2 * k + half;
    float c0 = -1e30f, c1 = -1e30f, c2 = -1e30f, c3 = -1e30f;
    float c4 = -1e30f, c5 = -1e30f, c6 = -1e30f, c7 = -1e30f;
#pragma unroll
    for (int s = 0; s < NS; s += 8) {
      int4 iv0 = *(const int4*)&sidx[mi * NS + s];
      int4 iv1 = *(const int4*)&sidx[mi * NS + s + 4];
      c0 = fmaxf(c0, Zb[(size_t)iv0.x * COUT + o]);
      c1 = fmaxf(c1, Zb[(size_t)iv0.y * COUT + o]);
      c2 = fmaxf(c2, Zb[(size_t)iv0.z * COUT + o]);
      c3 = fmaxf(c3, Zb[(size_t)iv0.w * COUT + o]);
      c4 = fmaxf(c4, Zb[(size_t)iv1.x * COUT + o]);
      c5 = fmaxf(c5, Zb[(size_t)iv1.y * COUT + o]);
      c6 = fmaxf(c6, Zb[(size_t)iv1.z * COUT + o]);
      c7 = fmaxf(c7, Zb[(size_t)iv1.w * COUT + o]);
    }
    float best = fmaxf(fmaxf(fmaxf(c0, c1), fmaxf(c2, c3)),
                       fmaxf(fmaxf(c4, c5), fmaxf(c6, c7)));
    float t = best + bo;
    t = (t - mo) * sc + bt;
    T[o][mi] = fmaxf(t, 0.0f);  // distinct (o,mi) per thread: race-free
  }
  __syncthreads();
  for (int l = 0; l < 4; ++l) {
    int e = l * 512 + (int)threadIdx.x;
    int mm = e & 7, oo = e >> 3;
    out[(size_t)(b * COUT + oo) * M_OUT + m0 + mm] = T[oo][mm];
  }
}

extern "C" void kernel_launch(void* const* d_in, const int* in_sizes, int n_in,
                              void* d_out, int out_size, void* d_ws, size_t ws_size,
                              hipStream_t stream) {
  const float* xyz      = (const float*)d_in[0];
  const float* features = (const float*)d_in[1];
  const float* W        = (const float*)d_in[2];
  const float* bias     = (const float*)d_in[3];
  const float* gamma    = (const float*)d_in[4];
  const float* beta     = (const float*)d_in[5];
  const float* rmean    = (const float*)d_in[6];
  const float* rvar     = (const float*)d_in[7];
  float* out = (float*)d_out;

  char* ws = (char*)d_ws;
  int* fps  = (int*)ws;                                  // 32 KB
  float* Z  = (float*)(ws + (64 << 10) + (2 << 20));     // 33.5 MB

  fps_conv_kernel<<<8 + 2048, 256, 0, stream>>>(xyz, fps, features, W, Z);
  ballq_pool_kernel<<<B_SZ * (M_OUT / 8), 512, 0, stream>>>(
      xyz, fps, Z, bias, gamma, beta, rmean, rvar, out);
}